// Round 1
// baseline (681.244 us; speedup 1.0000x reference)
//
#include <hip/hip_runtime.h>
#include <stdint.h>

#define B_SZ 2
#define S_LEN 2048
#define D_DIM 2048
#define NHEAD 16
#define HD 128
#define HALF 64
#define MROWS (B_SZ * S_LEN)   // 4096

typedef __attribute__((ext_vector_type(8))) __bf16 bf16x8;
typedef __attribute__((ext_vector_type(8))) short s16x8;
typedef __attribute__((ext_vector_type(8))) unsigned short u16x8;
typedef __attribute__((ext_vector_type(4))) float f32x4;

__device__ inline unsigned short f2bf(float x) {
  union { float f; uint32_t u; } c; c.f = x;
  uint32_t r = (c.u + 0x7fffu + ((c.u >> 16) & 1u)) >> 16;
  return (unsigned short)r;
}

__device__ inline void gll16(const void* g, void* l) {
  __builtin_amdgcn_global_load_lds(
      (const __attribute__((address_space(1))) void*)g,
      (__attribute__((address_space(3))) void*)l,
      16, 0, 0);
}

// ---------------- elementwise cast f32 -> bf16 ----------------
__global__ void cast_kernel(const float* __restrict__ in,
                            unsigned short* __restrict__ out, int n4) {
  int i = blockIdx.x * blockDim.x + threadIdx.x;
  int stride = gridDim.x * blockDim.x;
  for (; i < n4; i += stride) {
    float4 v = reinterpret_cast<const float4*>(in)[i];
    ushort4 o;
    o.x = f2bf(v.x); o.y = f2bf(v.y); o.z = f2bf(v.z); o.w = f2bf(v.w);
    reinterpret_cast<ushort4*>(out)[i] = o;
  }
}

// ---------------- GEMM: C[i,j] = sum_k A[i,k]*Bt[j,k] + bias[j] ----------------
// A: MxK bf16 row-major, Bt: NxK bf16 row-major. 128x128 tile, BK=32,
// global_load_lds staging (linear LDS), 4 waves each computing 64x64.
template <typename OutT>
__global__ __launch_bounds__(256) void gemm_bt(
    const unsigned short* __restrict__ A, const unsigned short* __restrict__ Bt,
    const float* __restrict__ bias, OutT* __restrict__ C,
    int M, int N, int K) {
  __shared__ __align__(16) unsigned short As[128 * 32];
  __shared__ __align__(16) unsigned short Bs[128 * 32];
  const int tid = threadIdx.x;
  const int lane = tid & 63;
  const int wave = tid >> 6;
  const int bm = blockIdx.y, bn = blockIdx.x;
  const int wr = wave >> 1, wc = wave & 1;
  const int lm = lane & 15, lg = lane >> 4;

  f32x4 acc[4][4] = {};

  for (int k0 = 0; k0 < K; k0 += 32) {
    __syncthreads();   // previous tile fully consumed
#pragma unroll
    for (int j = 0; j < 2; ++j) {
      int ob = wave * 2048 + j * 1024;        // byte base in 8KB tile
      int o = ob + lane * 16;                 // this lane's byte
      int row = o >> 6;                       // 64B per row (32 bf16)
      int col = (o & 63) >> 1;                // element col
      const unsigned short* ga = A + (size_t)(bm * 128 + row) * K + k0 + col;
      gll16(ga, (char*)As + ob);
      const unsigned short* gb = Bt + (size_t)(bn * 128 + row) * K + k0 + col;
      gll16(gb, (char*)Bs + ob);
    }
    __syncthreads();   // compiler drains vmcnt before barrier

    bf16x8 af[4], bfr[4];
#pragma unroll
    for (int mi = 0; mi < 4; ++mi)
      af[mi] = *reinterpret_cast<const bf16x8*>(
          &As[(wr * 64 + mi * 16 + lm) * 32 + lg * 8]);
#pragma unroll
    for (int ni = 0; ni < 4; ++ni)
      bfr[ni] = *reinterpret_cast<const bf16x8*>(
          &Bs[(wc * 64 + ni * 16 + lm) * 32 + lg * 8]);
#pragma unroll
    for (int mi = 0; mi < 4; ++mi)
#pragma unroll
      for (int ni = 0; ni < 4; ++ni)
        acc[mi][ni] = __builtin_amdgcn_mfma_f32_16x16x32_bf16(
            af[mi], bfr[ni], acc[mi][ni], 0, 0, 0);
  }

  // epilogue: bias + store
#pragma unroll
  for (int ni = 0; ni < 4; ++ni) {
    int col = bn * 128 + wc * 64 + ni * 16 + lm;
    float bv = bias[col];
#pragma unroll
    for (int mi = 0; mi < 4; ++mi) {
#pragma unroll
      for (int r = 0; r < 4; ++r) {
        int row = bm * 128 + wr * 64 + mi * 16 + lg * 4 + r;
        float v = acc[mi][ni][r] + bv;
        if constexpr (sizeof(OutT) == 2)
          C[(size_t)row * N + col] = (OutT)f2bf(v);
        else
          C[(size_t)row * N + col] = v;
      }
    }
  }
}

// ---------------- RMSNorm (full D) + RoPE, fp32 in -> bf16 out ----------------
__global__ __launch_bounds__(256) void norm_rope(
    const float* __restrict__ h, const float* __restrict__ w,
    const float* __restrict__ cosb, const float* __restrict__ sinb,
    unsigned short* __restrict__ out) {
  const int row = blockIdx.x;               // 0..MROWS-1
  const int pos = row & (S_LEN - 1);
  const float* hr = h + (size_t)row * D_DIM;
  const int t = threadIdx.x;
  const int d = t * 8;

  float4 v0 = *reinterpret_cast<const float4*>(hr + d);
  float4 v1 = *reinterpret_cast<const float4*>(hr + d + 4);
  float ss = v0.x * v0.x + v0.y * v0.y + v0.z * v0.z + v0.w * v0.w +
             v1.x * v1.x + v1.y * v1.y + v1.z * v1.z + v1.w * v1.w;
#pragma unroll
  for (int off = 32; off > 0; off >>= 1) ss += __shfl_down(ss, off);
  __shared__ float red[4];
  if ((t & 63) == 0) red[t >> 6] = ss;
  __syncthreads();
  float tot = red[0] + red[1] + red[2] + red[3];
  float inv = rsqrtf(tot * (1.0f / D_DIM) + 1e-6f);

  const int p = (d & (HD - 1)) >> 1;        // pair index within head
  const float* cp = cosb + pos * HALF + p;
  const float* sp = sinb + pos * HALF + p;
  const float* wp = w + d;

  float c0 = cp[0], c1 = cp[1], c2 = cp[2], c3 = cp[3];
  float s0 = sp[0], s1 = sp[1], s2 = sp[2], s3 = sp[3];
  float a0 = v0.x * inv * wp[0];
  float a1 = v0.y * inv * wp[1];
  float a2 = v0.z * inv * wp[2];
  float a3 = v0.w * inv * wp[3];
  float a4 = v1.x * inv * wp[4];
  float a5 = v1.y * inv * wp[5];
  float a6 = v1.z * inv * wp[6];
  float a7 = v1.w * inv * wp[7];
  u16x8 o;
  o[0] = f2bf(a0 * c0 - a1 * s0);
  o[1] = f2bf(a0 * s0 + a1 * c0);
  o[2] = f2bf(a2 * c1 - a3 * s1);
  o[3] = f2bf(a2 * s1 + a3 * c1);
  o[4] = f2bf(a4 * c2 - a5 * s2);
  o[5] = f2bf(a4 * s2 + a5 * c2);
  o[6] = f2bf(a6 * c3 - a7 * s3);
  o[7] = f2bf(a6 * s3 + a7 * c3);
  *reinterpret_cast<u16x8*>(out + (size_t)row * D_DIM + d) = o;
}

// ---------------- flash attention, 1 wave / block, QBLK=16, KVBLK=32 ----------------
__global__ __launch_bounds__(64) void attn_kernel(
    const unsigned short* __restrict__ Q, const unsigned short* __restrict__ K,
    const unsigned short* __restrict__ V, unsigned short* __restrict__ O) {
  const int lane = threadIdx.x;
  const int lm = lane & 15, lg = lane >> 4;
  const int qt = blockIdx.x;
  const int h = blockIdx.y;
  const int b = blockIdx.z;
  const size_t base = ((size_t)b * S_LEN) * D_DIM + (size_t)h * HD;
  const int q0 = qt * 16;

  bf16x8 qf[4];
#pragma unroll
  for (int kc = 0; kc < 4; ++kc)
    qf[kc] = *reinterpret_cast<const bf16x8*>(
        Q + base + (size_t)(q0 + lm) * D_DIM + kc * 32 + lg * 8);

  f32x4 oacc[8] = {};
  float mrow[4], lrow[4];
#pragma unroll
  for (int r = 0; r < 4; ++r) { mrow[r] = -3e38f; lrow[r] = 0.f; }

  __shared__ __align__(16) unsigned short P[16][56];
  const float scale = 0.08838834764831845f;   // 1/sqrt(128)

  for (int kt = 0; kt < S_LEN; kt += 32) {
    f32x4 sc0 = {}, sc1 = {};
#pragma unroll
    for (int kc = 0; kc < 4; ++kc) {
      bf16x8 kf0 = *reinterpret_cast<const bf16x8*>(
          K + base + (size_t)(kt + lm) * D_DIM + kc * 32 + lg * 8);
      bf16x8 kf1 = *reinterpret_cast<const bf16x8*>(
          K + base + (size_t)(kt + 16 + lm) * D_DIM + kc * 32 + lg * 8);
      sc0 = __builtin_amdgcn_mfma_f32_16x16x32_bf16(qf[kc], kf0, sc0, 0, 0, 0);
      sc1 = __builtin_amdgcn_mfma_f32_16x16x32_bf16(qf[kc], kf1, sc1, 0, 0, 0);
    }
    float p0[4], p1[4], alpha[4];
#pragma unroll
    for (int r = 0; r < 4; ++r) {
      float a = sc0[r] * scale, bb = sc1[r] * scale;
      sc0[r] = a; sc1[r] = bb;
      float mx = fmaxf(a, bb);
#pragma unroll
      for (int off = 8; off >= 1; off >>= 1) mx = fmaxf(mx, __shfl_xor(mx, off));
      float nm = fmaxf(mrow[r], mx);
      alpha[r] = __expf(mrow[r] - nm);
      p0[r] = __expf(sc0[r] - nm);
      p1[r] = __expf(sc1[r] - nm);
      float sm = p0[r] + p1[r];
#pragma unroll
      for (int off = 8; off >= 1; off >>= 1) sm += __shfl_xor(sm, off);
      lrow[r] = lrow[r] * alpha[r] + sm;
      mrow[r] = nm;
    }
#pragma unroll
    for (int dc = 0; dc < 8; ++dc)
#pragma unroll
      for (int r = 0; r < 4; ++r) oacc[dc][r] *= alpha[r];

#pragma unroll
    for (int r = 0; r < 4; ++r) {
      P[lg * 4 + r][lm] = f2bf(p0[r]);
      P[lg * 4 + r][16 + lm] = f2bf(p1[r]);
    }
    __syncthreads();
    bf16x8 pa = *reinterpret_cast<const bf16x8*>(&P[lm][lg * 8]);
    __syncthreads();

#pragma unroll
    for (int dc = 0; dc < 8; ++dc) {
      s16x8 vs;
#pragma unroll
      for (int e = 0; e < 8; ++e)
        vs[e] = (short)V[base + (size_t)(kt + lg * 8 + e) * D_DIM + dc * 16 + lm];
      bf16x8 vf = __builtin_bit_cast(bf16x8, vs);
      oacc[dc] = __builtin_amdgcn_mfma_f32_16x16x32_bf16(pa, vf, oacc[dc], 0, 0, 0);
    }
  }

#pragma unroll
  for (int dc = 0; dc < 8; ++dc)
#pragma unroll
    for (int r = 0; r < 4; ++r) {
      size_t idx = base + (size_t)(q0 + lg * 4 + r) * D_DIM + dc * 16 + lm;
      O[idx] = f2bf(oacc[dc][r] / lrow[r]);
    }
}

// ---------------- launch ----------------
extern "C" void kernel_launch(void* const* d_in, const int* in_sizes, int n_in,
                              void* d_out, int out_size, void* d_ws, size_t ws_size,
                              hipStream_t stream) {
  const float* x   = (const float*)d_in[0];
  const float* fc  = (const float*)d_in[1];
  const float* fs  = (const float*)d_in[2];
  const float* qw  = (const float*)d_in[3];
  const float* qb  = (const float*)d_in[4];
  const float* kw  = (const float*)d_in[5];
  const float* kb  = (const float*)d_in[6];
  const float* vw  = (const float*)d_in[7];
  const float* vb  = (const float*)d_in[8];
  const float* ow  = (const float*)d_in[9];
  const float* ob  = (const float*)d_in[10];
  const float* qnw = (const float*)d_in[11];
  const float* knw = (const float*)d_in[12];
  float* out = (float*)d_out;

  const size_t MSD = (size_t)MROWS * D_DIM;        // 8,388,608
  const size_t WSZ = (size_t)D_DIM * D_DIM;        // 4,194,304
  char* ws = (char*)d_ws;
  unsigned short* xb   = (unsigned short*)ws; ws += MSD * 2;
  unsigned short* qwb  = (unsigned short*)ws; ws += WSZ * 2;
  unsigned short* kwb  = (unsigned short*)ws; ws += WSZ * 2;
  unsigned short* vwb  = (unsigned short*)ws; ws += WSZ * 2;
  unsigned short* owb  = (unsigned short*)ws; ws += WSZ * 2;
  float*          qf   = (float*)ws;          ws += MSD * 4;
  unsigned short* qb16 = (unsigned short*)ws; ws += MSD * 2;
  unsigned short* kb16 = (unsigned short*)ws; ws += MSD * 2;
  unsigned short* vb16 = (unsigned short*)ws; ws += MSD * 2;
  unsigned short* ob16 = (unsigned short*)ws; ws += MSD * 2;

  cast_kernel<<<2048, 256, 0, stream>>>(x, xb, (int)(MSD / 4));
  cast_kernel<<<1024, 256, 0, stream>>>(qw, qwb, (int)(WSZ / 4));
  cast_kernel<<<1024, 256, 0, stream>>>(kw, kwb, (int)(WSZ / 4));
  cast_kernel<<<1024, 256, 0, stream>>>(vw, vwb, (int)(WSZ / 4));
  cast_kernel<<<1024, 256, 0, stream>>>(ow, owb, (int)(WSZ / 4));

  dim3 ggrid(D_DIM / 128, MROWS / 128);   // (16, 32)
  gemm_bt<unsigned short><<<ggrid, 256, 0, stream>>>(xb, vwb, vb, vb16,
                                                     MROWS, D_DIM, D_DIM);
  gemm_bt<float><<<ggrid, 256, 0, stream>>>(xb, qwb, qb, qf, MROWS, D_DIM, D_DIM);
  norm_rope<<<MROWS, 256, 0, stream>>>(qf, qnw, fc, fs, qb16);
  gemm_bt<float><<<ggrid, 256, 0, stream>>>(xb, kwb, kb, qf, MROWS, D_DIM, D_DIM);
  norm_rope<<<MROWS, 256, 0, stream>>>(qf, knw, fc, fs, kb16);

  attn_kernel<<<dim3(S_LEN / 16, NHEAD, B_SZ), 64, 0, stream>>>(qb16, kb16, vb16, ob16);

  gemm_bt<float><<<ggrid, 256, 0, stream>>>(ob16, owb, ob, out, MROWS, D_DIM, D_DIM);
}